// Round 11
// baseline (859.109 us; speedup 1.0000x reference)
//
#include <hip/hip_runtime.h>
#include <math.h>

// clDice loss on MI355X (gfx950).
// soft_skeletonize = 20 iterations of:
//   m = minpool3(x); contour = relu(maxpool3(m) - m); x = relu(x - contour)
// Round-21 == round-20 resubmit (round-20 died on GPUAcquisitionTimeout;
// never ran). K=5 (4 launches). Ledger: latency knee found -- >=4
// blocks/CU gives ~2.0 ns/block-iter, 2/CU gives ~2.5 (r8 vs r9); BH
// growth pays in residency. K is the lever that cuts work without cutting
// residency: 20 iters = 4 launches x K=5; block-iters 225280 -> 192512
// (-14.5%) and one whole launch of intermediate read+write (~128MB)
// vanishes. Register check: state 100 VGPR + ~20 temps ~= 120 <= 128
// budget from waves_per_eu(4,8). Gate: FETCH_SIZE (scratch spills balloon
// it, r4 signature). K-generalization edits: top-stage rmask
// y-(4*(K-1)+1), output lag y-19, y0 = r0-10. partials MOVED to B region:
// with 4 launches the last launch reads A (A live!), B is dead there.
// Per-iter engine unchanged from r9: BH=64, single-buffered edges,
// 2 barriers/iter, unroll-4, interior-band mask elision, prefetch.
// Predicted: ~115-125 us/launch x4, total ~470-510; FETCH ~96MB/launch.
// Failure: FETCH >> 100MB or >=140 us/launch -> spills -> revert K=4.

#define IMG_H 1024
#define IMG_W 1024
#define IMG_N (IMG_H * IMG_W)
#define NIMG  16
#define NZ    32                    // 16 pred + 16 gt images
#define BH    64                    // output rows per band
#define NBANDS (IMG_H / BH)         // 16
#define K     5                     // fused skeleton iterations per launch
#define EW    258                   // 256 lanes + 2 guard slots
#define NBLK  (NZ * NBANDS)         // 512 blocks per launch
#define NITER (BH + 6 * K)          // 94 row-iterations

typedef _Float16 h2 __attribute__((ext_vector_type(2)));

__device__ __forceinline__ h2 hmin2(h2 a, h2 b) { return __builtin_elementwise_min(a, b); }
__device__ __forceinline__ h2 hmax2(h2 a, h2 b) { return __builtin_elementwise_max(a, b); }

union U32H { unsigned u; h2 h; };
__device__ __forceinline__ unsigned as_u(h2 h) { U32H t; t.h = h; return t.u; }
__device__ __forceinline__ h2 as_h2(unsigned u) { U32H t; t.u = u; return t.h; }

struct Hp { h2 lo, hi; };           // 4 image columns per lane
struct St { Hp hm1, hm2, m2, m3, q1, q2, x1, x2, x3, xc; };

// One pipeline stage. rmask: +inf pass / -inf force (maxpool row padding);
// only applied when MASKED (edge bands). Edge pair layout:
// e2[slot].x = {x_col0, m_col0} (read by LEFT-seeking neighbor at t+2);
// e2[slot].y = {x_col3, m_col3} (read at slot t). Single-buffered: caller
// guarantees barriers between prev writes / these reads / next writes.
template<int MASKED>
__device__ __forceinline__ Hp stage_step(
    St& s, h2 rmask, int t, const uint2 (&e2)[EW])
{
    h2 lp = as_h2(e2[t].y);        // left nbr's col3 {x, m}
    h2 rp = as_h2(e2[t + 2].x);    // right nbr's col0 {x, m}
    // h-min3 of x row
    h2 midx = (h2){s.xc.lo[1], s.xc.hi[0]};               // {x1, x2}
    h2 hlo = hmin2(hmin2((h2){lp[0], s.xc.lo[0]}, s.xc.lo), midx);
    h2 hhi = hmin2(hmin2(midx, s.xc.hi), (h2){s.xc.hi[1], rp[0]});
    // v-min3 (+ row-validity mask on edge bands only)
    h2 mlo, mhi;
    if constexpr (MASKED) {
        mlo = hmin2(hmin2(hmin2(s.hm1.lo, s.hm2.lo), hlo), rmask);
        mhi = hmin2(hmin2(hmin2(s.hm1.hi, s.hm2.hi), hhi), rmask);
    } else {
        mlo = hmin2(hmin2(s.hm1.lo, s.hm2.lo), hlo);
        mhi = hmin2(hmin2(s.hm1.hi, s.hm2.hi), hhi);
    }
    // h-max3 of m (previous iter's m, in m2; neighbor edges from LDS)
    h2 midm = (h2){s.m2.lo[1], s.m2.hi[0]};
    h2 qlo = hmax2(hmax2((h2){lp[1], s.m2.lo[0]}, s.m2.lo), midm);
    h2 qhi = hmax2(hmax2(midm, s.m2.hi), (h2){s.m2.hi[1], rp[1]});
    // v-max3
    h2 Mlo = hmax2(hmax2(s.q1.lo, s.q2.lo), qlo);
    h2 Mhi = hmax2(hmax2(s.q1.hi, s.q2.hi), qhi);
    // contour + relu update
    const h2 Z2 = (h2){(_Float16)0.f, (_Float16)0.f};
    h2 elo = hmax2(s.x3.lo - hmax2(Mlo - s.m3.lo, Z2), Z2);
    h2 ehi = hmax2(s.x3.hi - hmax2(Mhi - s.m3.hi, Z2), Z2);
    // ring shifts
    s.hm1 = s.hm2; s.hm2.lo = hlo; s.hm2.hi = hhi;
    s.m3  = s.m2;  s.m2.lo  = mlo; s.m2.hi  = mhi;
    s.q1  = s.q2;  s.q2.lo  = qlo; s.q2.hi  = qhi;
    s.x3  = s.x2;  s.x2 = s.x1;    s.x1 = s.xc;
    Hp e; e.lo = elo; e.hi = ehi;
    return e;
}

// Load one input row. MASKED: +inf outside the image. Unmasked (interior
// bands): every touched row is provably in-bounds -> unconditional load.
template<int FIRST, int MASKED>
__device__ __forceinline__ Hp load_row(
    int y, int c, const float* __restrict__ f32src,
    const unsigned short* __restrict__ bsrc)
{
    const _Float16 HINF = (_Float16)__builtin_huge_valf();
    Hp x; x.lo = (h2){HINF, HINF}; x.hi = (h2){HINF, HINF};
    if (!MASKED || (unsigned)y < (unsigned)IMG_H) {
        if constexpr (FIRST) {
            float4 f = *(const float4*)(f32src + (size_t)y * IMG_W + c);
            x.lo = (h2){(_Float16)f.x, (_Float16)f.y};
            x.hi = (h2){(_Float16)f.z, (_Float16)f.w};
        } else {
            uint2 u = *(const uint2*)(bsrc + (size_t)y * IMG_W + c);
            x.lo = as_h2(u.x);
            x.hi = as_h2(u.y);
        }
    }
    return x;
}

template<int FIRST, int LAST, int MASKED>
__device__ __forceinline__ void iter_step(
    int y, int t, int c, int r0, St (&st)[K], Hp& xn,
    const float* __restrict__ f32src, const unsigned short* __restrict__ bsrc,
    unsigned short* __restrict__ bdst, const float* __restrict__ oth,
    float& a1, float& a2, uint2 (&e2)[K][EW])
{
    const _Float16 HINF = (_Float16)__builtin_huge_valf();
    const h2 PINF2 = (h2){HINF, HINF};
    const h2 NINF2 = (h2){-HINF, -HINF};

    // issue the row-(y+2) load now; its value is consumed NEXT iteration,
    // so the global-load latency spans a full iteration body.
    Hp tnext = load_row<FIRST, MASKED>(y + 2, c, f32src, bsrc);

    __syncthreads();                         // prev-iter edge writes visible

    h2 rm = PINF2;
    if constexpr (MASKED)
        rm = ((unsigned)(y - (4 * (K - 1) + 1)) < (unsigned)IMG_H) ? PINF2 : NINF2;
    Hp eK = stage_step<MASKED>(st[K - 1], rm, t, e2[K - 1]);
    #pragma unroll
    for (int k = K - 2; k >= 0; --k) {
        if constexpr (MASKED)
            rm = ((unsigned)(y - 4 * k - 1) < (unsigned)IMG_H) ? PINF2 : NINF2;
        Hp e = stage_step<MASKED>(st[k], rm, t, e2[k]);
        if constexpr (MASKED) {
            h2 em = ((unsigned)(y - 4 * k - 3) < (unsigned)IMG_H) ? NINF2 : PINF2;
            st[k + 1].xc.lo = hmax2(e.lo, em);   // max(e,-inf)=e; max(e,+inf)=+inf
            st[k + 1].xc.hi = hmax2(e.hi, em);
        } else {
            st[k + 1].xc = e;
        }
    }
    st[0].xc = xn;                           // row y+1, loaded last iteration
    xn = tnext;

    __syncthreads();                         // all edge reads done

    // edge writes for next iteration (new xc + this iter's m, now in m2)
    #pragma unroll
    for (int k = 0; k < K; ++k) {
        e2[k][t + 1] = make_uint2(
            as_u((h2){st[k].xc.lo[0], st[k].m2.lo[0]}),
            as_u((h2){st[k].xc.hi[1], st[k].m2.hi[1]}));
    }

    int orow = y - (4 * (K - 1) + 3);        // y - 19
    if ((unsigned)(orow - r0) < (unsigned)BH) {
        if constexpr (!LAST) {
            *(uint2*)(bdst + (size_t)orow * IMG_W + c) =
                make_uint2(as_u(eK.lo), as_u(eK.hi));
        } else {
            float4 ov = *(const float4*)(oth + (size_t)orow * IMG_W + c);
            float e0 = (float)eK.lo[0], e1 = (float)eK.lo[1];
            float e2f = (float)eK.hi[0], e3 = (float)eK.hi[1];
            a1 += e0 * ov.x + e1 * ov.y + e2f * ov.z + e3 * ov.w;
            a2 += e0 + e1 + e2f + e3;
        }
    }
}

template<int FIRST, int LAST>
__global__ __attribute__((amdgpu_waves_per_eu(4, 8)))
__launch_bounds__(256) void skel(
    const unsigned short* __restrict__ src, unsigned short* __restrict__ dst,
    const float* __restrict__ pred32, const float* __restrict__ gt32,
    double* __restrict__ partials)
{
    __shared__ uint2 e2[K][EW];       // single-buffered edge exchange
    __shared__ double l1[4], l2[4];

    const int t = threadIdx.x, c = 4 * t;
    const int band = blockIdx.x, z = blockIdx.y;
    const int r0 = band * BH;
    const _Float16 HINF = (_Float16)__builtin_huge_valf();
    const h2 PINF2 = (h2){HINF, HINF};
    const h2 NINF2 = (h2){-HINF, -HINF};

    const float* f32src = (z < NIMG) ? pred32 + (size_t)z * IMG_N
                                     : gt32 + (size_t)(z - NIMG) * IMG_N;
    const unsigned short* bsrc = FIRST ? nullptr : src + (size_t)z * IMG_N;
    unsigned short* bdst = LAST ? nullptr : dst + (size_t)z * IMG_N;
    const float* oth = LAST ? ((z < NIMG) ? gt32 + (size_t)z * IMG_N
                                          : pred32 + (size_t)(z - NIMG) * IMG_N)
                            : nullptr;

    if (t < K) {
        // guard pairs: x=+inf (0x7C00 low), m=-inf (0xFC00 high)
        e2[t][0]      = make_uint2(0u, 0xFC007C00u);  // only .y read
        e2[t][EW - 1] = make_uint2(0xFC007C00u, 0u);  // only .x read
    }

    St st[K];
    #pragma unroll
    for (int k = 0; k < K; ++k) {
        st[k].hm1.lo = st[k].hm1.hi = PINF2;
        st[k].hm2.lo = st[k].hm2.hi = PINF2;
        st[k].m2.lo  = st[k].m2.hi  = NINF2;
        st[k].m3.lo  = st[k].m3.hi  = NINF2;
        st[k].q1.lo  = st[k].q1.hi  = NINF2;
        st[k].q2.lo  = st[k].q2.hi  = NINF2;
        st[k].x1.lo  = st[k].x1.hi  = PINF2;
        st[k].x2.lo  = st[k].x2.hi  = PINF2;
        st[k].x3.lo  = st[k].x3.hi  = PINF2;
        st[k].xc.lo  = st[k].xc.hi  = PINF2;
    }

    const int y0 = r0 - 2 * K;
    st[0].xc = load_row<FIRST, 1>(y0, c, f32src, bsrc);      // masked: cheap, once
    Hp xn    = load_row<FIRST, 1>(y0 + 1, c, f32src, bsrc);

    // prologue edge write (consumed by first iteration after its barrier)
    #pragma unroll
    for (int k = 0; k < K; ++k) {
        e2[k][t + 1] = make_uint2(
            as_u((h2){st[k].xc.lo[0], st[k].m2.lo[0]}),
            as_u((h2){st[k].xc.hi[1], st[k].m2.hi[1]}));
    }

    float a1 = 0.f, a2 = 0.f;
    // Interior bands (1..NBANDS-2): every rm/em mask and load bound is
    // provably constant across the whole y-range incl. warm-up
    // (y in [r0-27, r0+85] within [0,1024) for r0 in [64, 896]).
    // unroll 4 = x-ring period: ring-shift copies vanish at back-edge.
    if (band >= 1 && band <= NBANDS - 2) {
        #pragma unroll 4
        for (int i = 0; i < NITER; ++i)
            iter_step<FIRST, LAST, 0>(y0 + i, t, c, r0, st, xn, f32src, bsrc, bdst, oth, a1, a2, e2);
    } else {
        #pragma unroll 4
        for (int i = 0; i < NITER; ++i)
            iter_step<FIRST, LAST, 1>(y0 + i, t, c, r0, st, xn, f32src, bsrc, bdst, oth, a1, a2, e2);
    }

    if constexpr (LAST) {                    // per-block partials (no atomics)
        double d1 = a1, d2 = a2;
        for (int off = 32; off; off >>= 1) {
            d1 += __shfl_down(d1, off);
            d2 += __shfl_down(d2, off);
        }
        const int w = t >> 6;
        if ((t & 63) == 0) { l1[w] = d1; l2[w] = d2; }
        __syncthreads();
        if (t == 0) {
            int bid = z * NBANDS + band;
            partials[2 * bid]     = l1[0] + l1[1] + l1[2] + l1[3];
            partials[2 * bid + 1] = l2[0] + l2[1] + l2[2] + l2[3];
        }
    }
}

__global__ __launch_bounds__(256) void finalize(
    const double* __restrict__ pp, float* __restrict__ out)
{
    __shared__ double sh[4][4];
    double i1 = 0, i2 = 0, t1 = 0, t2 = 0;
    for (int i = threadIdx.x; i < NBLK; i += 256) {
        double a = pp[2 * i], b = pp[2 * i + 1];
        if (i < NIMG * NBANDS) { i1 += a; i2 += b; }   // z < 16: cl_pred side
        else                   { t1 += a; t2 += b; }   // z >= 16: skel_gt side
    }
    for (int off = 32; off; off >>= 1) {
        i1 += __shfl_down(i1, off); i2 += __shfl_down(i2, off);
        t1 += __shfl_down(t1, off); t2 += __shfl_down(t2, off);
    }
    const int w = threadIdx.x >> 6;
    if ((threadIdx.x & 63) == 0) { sh[0][w] = i1; sh[1][w] = i2; sh[2][w] = t1; sh[3][w] = t2; }
    __syncthreads();
    if (threadIdx.x == 0) {
        double s1 = 0, s2 = 0, s3 = 0, s4 = 0;
        for (int j = 0; j < 4; ++j) { s1 += sh[0][j]; s2 += sh[1][j]; s3 += sh[2][j]; s4 += sh[3][j]; }
        double iflat = (s1 + 1.0) / (s2 + 1.0);
        double tflat = (s3 + 1.0) / (s4 + 1.0);
        out[0] = (float)(1.0 - 2.0 * (iflat * tflat) / (iflat + tflat));
    }
}

extern "C" void kernel_launch(void* const* d_in, const int* in_sizes, int n_in,
                              void* d_out, int out_size, void* d_ws, size_t ws_size,
                              hipStream_t stream)
{
    const float* pred = (const float*)d_in[0];
    const float* gt   = (const float*)d_in[1];

    unsigned short* A = (unsigned short*)d_ws;            // 32 f16 images (64 MiB)
    unsigned short* B = A + (size_t)NZ * IMG_N;           // 32 f16 images
    // partials live in the B region: launch 4 reads A (A live!), B is dead.
    double* partials  = (double*)B;
    dim3 grid(NBANDS, NZ);                                // 16 bands x 32 images

    skel<1, 0><<<grid, 256, 0, stream>>>(nullptr, A, pred, gt, nullptr);  // iters 1-5
    skel<0, 0><<<grid, 256, 0, stream>>>(A, B, pred, gt, nullptr);        // 6-10
    skel<0, 0><<<grid, 256, 0, stream>>>(B, A, pred, gt, nullptr);        // 11-15
    skel<0, 1><<<grid, 256, 0, stream>>>(A, nullptr, pred, gt, partials); // 16-20 + sums

    finalize<<<1, 256, 0, stream>>>(partials, (float*)d_out);
}

// Round 12
// 854.518 us; speedup vs baseline: 1.0054x; 1.0054x over previous
//
#include <hip/hip_runtime.h>
#include <math.h>

// clDice loss on MI355X (gfx950).
// soft_skeletonize = 20 iterations of:
//   m = minpool3(x); contour = relu(maxpool3(m) - m); x = relu(x - contour)
// Round-22: K=5 with the REAL register budget. Round-11(K=5) post-mortem:
// amdgpu_waves_per_eu(4,8) makes the allocator target max=8 waves/EU ->
// 64-VGPR budget; K=5's ~120 live state spilled (VGPR=64 reported,
// per-stage 0.61->1.03ns, VALUBusy 36%, 248us/launch). L2 absorbed the
// spill traffic (FETCH only +22MB) but the latency poisoned the loop.
// Budget ledger: (8)->64 regs/spills (r4 collapse); (4,4)->128 regs,
// VGPR=60 clean (r1); (4,8)->64 regs, spills iff state>64 (r11).
// This round, single variable: (4,8) -> (4,4). K=5 state ~120 <= 128.
// Max 4 waves/EU is irrelevant: BH=64 grid supplies 2 blocks/CU anyway.
// Gate: VGPR_Count MUST be >64 (spills gone). Predicted: VGPR 100-128,
// FETCH ~96MB, ~110-130us/launch, total ~470-530. Failure: VGPR<=64 or
// >=150us -> K=5 unviable -> revert to r9 (K=4/BH=64, 561us).
// Per-iter engine unchanged: BH=64, single-buffered edges, 2 barriers/
// iter, unroll-4, interior-band mask elision, prefetch, 4 launches,
// partials in B region (last launch reads A).

#define IMG_H 1024
#define IMG_W 1024
#define IMG_N (IMG_H * IMG_W)
#define NIMG  16
#define NZ    32                    // 16 pred + 16 gt images
#define BH    64                    // output rows per band
#define NBANDS (IMG_H / BH)         // 16
#define K     5                     // fused skeleton iterations per launch
#define EW    258                   // 256 lanes + 2 guard slots
#define NBLK  (NZ * NBANDS)         // 512 blocks per launch
#define NITER (BH + 6 * K)          // 94 row-iterations

typedef _Float16 h2 __attribute__((ext_vector_type(2)));

__device__ __forceinline__ h2 hmin2(h2 a, h2 b) { return __builtin_elementwise_min(a, b); }
__device__ __forceinline__ h2 hmax2(h2 a, h2 b) { return __builtin_elementwise_max(a, b); }

union U32H { unsigned u; h2 h; };
__device__ __forceinline__ unsigned as_u(h2 h) { U32H t; t.h = h; return t.u; }
__device__ __forceinline__ h2 as_h2(unsigned u) { U32H t; t.u = u; return t.h; }

struct Hp { h2 lo, hi; };           // 4 image columns per lane
struct St { Hp hm1, hm2, m2, m3, q1, q2, x1, x2, x3, xc; };

// One pipeline stage. rmask: +inf pass / -inf force (maxpool row padding);
// only applied when MASKED (edge bands). Edge pair layout:
// e2[slot].x = {x_col0, m_col0} (read by LEFT-seeking neighbor at t+2);
// e2[slot].y = {x_col3, m_col3} (read at slot t). Single-buffered: caller
// guarantees barriers between prev writes / these reads / next writes.
template<int MASKED>
__device__ __forceinline__ Hp stage_step(
    St& s, h2 rmask, int t, const uint2 (&e2)[EW])
{
    h2 lp = as_h2(e2[t].y);        // left nbr's col3 {x, m}
    h2 rp = as_h2(e2[t + 2].x);    // right nbr's col0 {x, m}
    // h-min3 of x row
    h2 midx = (h2){s.xc.lo[1], s.xc.hi[0]};               // {x1, x2}
    h2 hlo = hmin2(hmin2((h2){lp[0], s.xc.lo[0]}, s.xc.lo), midx);
    h2 hhi = hmin2(hmin2(midx, s.xc.hi), (h2){s.xc.hi[1], rp[0]});
    // v-min3 (+ row-validity mask on edge bands only)
    h2 mlo, mhi;
    if constexpr (MASKED) {
        mlo = hmin2(hmin2(hmin2(s.hm1.lo, s.hm2.lo), hlo), rmask);
        mhi = hmin2(hmin2(hmin2(s.hm1.hi, s.hm2.hi), hhi), rmask);
    } else {
        mlo = hmin2(hmin2(s.hm1.lo, s.hm2.lo), hlo);
        mhi = hmin2(hmin2(s.hm1.hi, s.hm2.hi), hhi);
    }
    // h-max3 of m (previous iter's m, in m2; neighbor edges from LDS)
    h2 midm = (h2){s.m2.lo[1], s.m2.hi[0]};
    h2 qlo = hmax2(hmax2((h2){lp[1], s.m2.lo[0]}, s.m2.lo), midm);
    h2 qhi = hmax2(hmax2(midm, s.m2.hi), (h2){s.m2.hi[1], rp[1]});
    // v-max3
    h2 Mlo = hmax2(hmax2(s.q1.lo, s.q2.lo), qlo);
    h2 Mhi = hmax2(hmax2(s.q1.hi, s.q2.hi), qhi);
    // contour + relu update
    const h2 Z2 = (h2){(_Float16)0.f, (_Float16)0.f};
    h2 elo = hmax2(s.x3.lo - hmax2(Mlo - s.m3.lo, Z2), Z2);
    h2 ehi = hmax2(s.x3.hi - hmax2(Mhi - s.m3.hi, Z2), Z2);
    // ring shifts
    s.hm1 = s.hm2; s.hm2.lo = hlo; s.hm2.hi = hhi;
    s.m3  = s.m2;  s.m2.lo  = mlo; s.m2.hi  = mhi;
    s.q1  = s.q2;  s.q2.lo  = qlo; s.q2.hi  = qhi;
    s.x3  = s.x2;  s.x2 = s.x1;    s.x1 = s.xc;
    Hp e; e.lo = elo; e.hi = ehi;
    return e;
}

// Load one input row. MASKED: +inf outside the image. Unmasked (interior
// bands): every touched row is provably in-bounds -> unconditional load.
template<int FIRST, int MASKED>
__device__ __forceinline__ Hp load_row(
    int y, int c, const float* __restrict__ f32src,
    const unsigned short* __restrict__ bsrc)
{
    const _Float16 HINF = (_Float16)__builtin_huge_valf();
    Hp x; x.lo = (h2){HINF, HINF}; x.hi = (h2){HINF, HINF};
    if (!MASKED || (unsigned)y < (unsigned)IMG_H) {
        if constexpr (FIRST) {
            float4 f = *(const float4*)(f32src + (size_t)y * IMG_W + c);
            x.lo = (h2){(_Float16)f.x, (_Float16)f.y};
            x.hi = (h2){(_Float16)f.z, (_Float16)f.w};
        } else {
            uint2 u = *(const uint2*)(bsrc + (size_t)y * IMG_W + c);
            x.lo = as_h2(u.x);
            x.hi = as_h2(u.y);
        }
    }
    return x;
}

template<int FIRST, int LAST, int MASKED>
__device__ __forceinline__ void iter_step(
    int y, int t, int c, int r0, St (&st)[K], Hp& xn,
    const float* __restrict__ f32src, const unsigned short* __restrict__ bsrc,
    unsigned short* __restrict__ bdst, const float* __restrict__ oth,
    float& a1, float& a2, uint2 (&e2)[K][EW])
{
    const _Float16 HINF = (_Float16)__builtin_huge_valf();
    const h2 PINF2 = (h2){HINF, HINF};
    const h2 NINF2 = (h2){-HINF, -HINF};

    // issue the row-(y+2) load now; its value is consumed NEXT iteration,
    // so the global-load latency spans a full iteration body.
    Hp tnext = load_row<FIRST, MASKED>(y + 2, c, f32src, bsrc);

    __syncthreads();                         // prev-iter edge writes visible

    h2 rm = PINF2;
    if constexpr (MASKED)
        rm = ((unsigned)(y - (4 * (K - 1) + 1)) < (unsigned)IMG_H) ? PINF2 : NINF2;
    Hp eK = stage_step<MASKED>(st[K - 1], rm, t, e2[K - 1]);
    #pragma unroll
    for (int k = K - 2; k >= 0; --k) {
        if constexpr (MASKED)
            rm = ((unsigned)(y - 4 * k - 1) < (unsigned)IMG_H) ? PINF2 : NINF2;
        Hp e = stage_step<MASKED>(st[k], rm, t, e2[k]);
        if constexpr (MASKED) {
            h2 em = ((unsigned)(y - 4 * k - 3) < (unsigned)IMG_H) ? NINF2 : PINF2;
            st[k + 1].xc.lo = hmax2(e.lo, em);   // max(e,-inf)=e; max(e,+inf)=+inf
            st[k + 1].xc.hi = hmax2(e.hi, em);
        } else {
            st[k + 1].xc = e;
        }
    }
    st[0].xc = xn;                           // row y+1, loaded last iteration
    xn = tnext;

    __syncthreads();                         // all edge reads done

    // edge writes for next iteration (new xc + this iter's m, now in m2)
    #pragma unroll
    for (int k = 0; k < K; ++k) {
        e2[k][t + 1] = make_uint2(
            as_u((h2){st[k].xc.lo[0], st[k].m2.lo[0]}),
            as_u((h2){st[k].xc.hi[1], st[k].m2.hi[1]}));
    }

    int orow = y - (4 * (K - 1) + 3);        // y - 19
    if ((unsigned)(orow - r0) < (unsigned)BH) {
        if constexpr (!LAST) {
            *(uint2*)(bdst + (size_t)orow * IMG_W + c) =
                make_uint2(as_u(eK.lo), as_u(eK.hi));
        } else {
            float4 ov = *(const float4*)(oth + (size_t)orow * IMG_W + c);
            float e0 = (float)eK.lo[0], e1 = (float)eK.lo[1];
            float e2f = (float)eK.hi[0], e3 = (float)eK.hi[1];
            a1 += e0 * ov.x + e1 * ov.y + e2f * ov.z + e3 * ov.w;
            a2 += e0 + e1 + e2f + e3;
        }
    }
}

template<int FIRST, int LAST>
__global__ __attribute__((amdgpu_waves_per_eu(4, 4)))
__launch_bounds__(256) void skel(
    const unsigned short* __restrict__ src, unsigned short* __restrict__ dst,
    const float* __restrict__ pred32, const float* __restrict__ gt32,
    double* __restrict__ partials)
{
    __shared__ uint2 e2[K][EW];       // single-buffered edge exchange
    __shared__ double l1[4], l2[4];

    const int t = threadIdx.x, c = 4 * t;
    const int band = blockIdx.x, z = blockIdx.y;
    const int r0 = band * BH;
    const _Float16 HINF = (_Float16)__builtin_huge_valf();
    const h2 PINF2 = (h2){HINF, HINF};
    const h2 NINF2 = (h2){-HINF, -HINF};

    const float* f32src = (z < NIMG) ? pred32 + (size_t)z * IMG_N
                                     : gt32 + (size_t)(z - NIMG) * IMG_N;
    const unsigned short* bsrc = FIRST ? nullptr : src + (size_t)z * IMG_N;
    unsigned short* bdst = LAST ? nullptr : dst + (size_t)z * IMG_N;
    const float* oth = LAST ? ((z < NIMG) ? gt32 + (size_t)z * IMG_N
                                          : pred32 + (size_t)(z - NIMG) * IMG_N)
                            : nullptr;

    if (t < K) {
        // guard pairs: x=+inf (0x7C00 low), m=-inf (0xFC00 high)
        e2[t][0]      = make_uint2(0u, 0xFC007C00u);  // only .y read
        e2[t][EW - 1] = make_uint2(0xFC007C00u, 0u);  // only .x read
    }

    St st[K];
    #pragma unroll
    for (int k = 0; k < K; ++k) {
        st[k].hm1.lo = st[k].hm1.hi = PINF2;
        st[k].hm2.lo = st[k].hm2.hi = PINF2;
        st[k].m2.lo  = st[k].m2.hi  = NINF2;
        st[k].m3.lo  = st[k].m3.hi  = NINF2;
        st[k].q1.lo  = st[k].q1.hi  = NINF2;
        st[k].q2.lo  = st[k].q2.hi  = NINF2;
        st[k].x1.lo  = st[k].x1.hi  = PINF2;
        st[k].x2.lo  = st[k].x2.hi  = PINF2;
        st[k].x3.lo  = st[k].x3.hi  = PINF2;
        st[k].xc.lo  = st[k].xc.hi  = PINF2;
    }

    const int y0 = r0 - 2 * K;
    st[0].xc = load_row<FIRST, 1>(y0, c, f32src, bsrc);      // masked: cheap, once
    Hp xn    = load_row<FIRST, 1>(y0 + 1, c, f32src, bsrc);

    // prologue edge write (consumed by first iteration after its barrier)
    #pragma unroll
    for (int k = 0; k < K; ++k) {
        e2[k][t + 1] = make_uint2(
            as_u((h2){st[k].xc.lo[0], st[k].m2.lo[0]}),
            as_u((h2){st[k].xc.hi[1], st[k].m2.hi[1]}));
    }

    float a1 = 0.f, a2 = 0.f;
    // Interior bands (1..NBANDS-2): every rm/em mask and load bound is
    // provably constant across the whole y-range incl. warm-up
    // (y in [r0-27, r0+85] within [0,1024) for r0 in [64, 896]).
    // unroll 4 = x-ring period: ring-shift copies vanish at back-edge.
    if (band >= 1 && band <= NBANDS - 2) {
        #pragma unroll 4
        for (int i = 0; i < NITER; ++i)
            iter_step<FIRST, LAST, 0>(y0 + i, t, c, r0, st, xn, f32src, bsrc, bdst, oth, a1, a2, e2);
    } else {
        #pragma unroll 4
        for (int i = 0; i < NITER; ++i)
            iter_step<FIRST, LAST, 1>(y0 + i, t, c, r0, st, xn, f32src, bsrc, bdst, oth, a1, a2, e2);
    }

    if constexpr (LAST) {                    // per-block partials (no atomics)
        double d1 = a1, d2 = a2;
        for (int off = 32; off; off >>= 1) {
            d1 += __shfl_down(d1, off);
            d2 += __shfl_down(d2, off);
        }
        const int w = t >> 6;
        if ((t & 63) == 0) { l1[w] = d1; l2[w] = d2; }
        __syncthreads();
        if (t == 0) {
            int bid = z * NBANDS + band;
            partials[2 * bid]     = l1[0] + l1[1] + l1[2] + l1[3];
            partials[2 * bid + 1] = l2[0] + l2[1] + l2[2] + l2[3];
        }
    }
}

__global__ __launch_bounds__(256) void finalize(
    const double* __restrict__ pp, float* __restrict__ out)
{
    __shared__ double sh[4][4];
    double i1 = 0, i2 = 0, t1 = 0, t2 = 0;
    for (int i = threadIdx.x; i < NBLK; i += 256) {
        double a = pp[2 * i], b = pp[2 * i + 1];
        if (i < NIMG * NBANDS) { i1 += a; i2 += b; }   // z < 16: cl_pred side
        else                   { t1 += a; t2 += b; }   // z >= 16: skel_gt side
    }
    for (int off = 32; off; off >>= 1) {
        i1 += __shfl_down(i1, off); i2 += __shfl_down(i2, off);
        t1 += __shfl_down(t1, off); t2 += __shfl_down(t2, off);
    }
    const int w = threadIdx.x >> 6;
    if ((threadIdx.x & 63) == 0) { sh[0][w] = i1; sh[1][w] = i2; sh[2][w] = t1; sh[3][w] = t2; }
    __syncthreads();
    if (threadIdx.x == 0) {
        double s1 = 0, s2 = 0, s3 = 0, s4 = 0;
        for (int j = 0; j < 4; ++j) { s1 += sh[0][j]; s2 += sh[1][j]; s3 += sh[2][j]; s4 += sh[3][j]; }
        double iflat = (s1 + 1.0) / (s2 + 1.0);
        double tflat = (s3 + 1.0) / (s4 + 1.0);
        out[0] = (float)(1.0 - 2.0 * (iflat * tflat) / (iflat + tflat));
    }
}

extern "C" void kernel_launch(void* const* d_in, const int* in_sizes, int n_in,
                              void* d_out, int out_size, void* d_ws, size_t ws_size,
                              hipStream_t stream)
{
    const float* pred = (const float*)d_in[0];
    const float* gt   = (const float*)d_in[1];

    unsigned short* A = (unsigned short*)d_ws;            // 32 f16 images (64 MiB)
    unsigned short* B = A + (size_t)NZ * IMG_N;           // 32 f16 images
    // partials live in the B region: launch 4 reads A (A live!), B is dead.
    double* partials  = (double*)B;
    dim3 grid(NBANDS, NZ);                                // 16 bands x 32 images

    skel<1, 0><<<grid, 256, 0, stream>>>(nullptr, A, pred, gt, nullptr);  // iters 1-5
    skel<0, 0><<<grid, 256, 0, stream>>>(A, B, pred, gt, nullptr);        // 6-10
    skel<0, 0><<<grid, 256, 0, stream>>>(B, A, pred, gt, nullptr);        // 11-15
    skel<0, 1><<<grid, 256, 0, stream>>>(A, nullptr, pred, gt, partials); // 16-20 + sums

    finalize<<<1, 256, 0, stream>>>(partials, (float*)d_out);
}

// Round 13
// 624.977 us; speedup vs baseline: 1.3746x; 1.3673x over previous
//
#include <hip/hip_runtime.h>
#include <math.h>

// clDice loss on MI355X (gfx950).
// soft_skeletonize = 20 iterations of:
//   m = minpool3(x); contour = relu(maxpool3(m) - m); x = relu(x - contour)
// Round-23: K=5, register budget via __launch_bounds__(256, 1).
// Ledger: amdgpu_waves_per_eu FAILED twice to lift the 64-VGPR clamp
// (r11 (4,8): VGPR=64, spills, 248us; r12 (4,4): VGPR=64, SGPR 32->112
// so the attr DID reach codegen, still spills, 239us). K=4's live set
// is <=64 (r8/r9: VGPR=64, zero spill -> FETCH matched model), so K=5
// demand is ~75-100. The documented knob for the budget is the SECOND
// launch_bounds arg = min waves/EU: (256, 1) -> budget 512 VGPR.
// Occupancy cost nil (BH=64 grid supplies 2 blocks/CU = 2 waves/EU).
// Third and FINAL K=5 attempt, decision pre-committed: VGPR>64 & ~110-
// 130us/launch -> keep; VGPR=64 again or >=150us -> revert to r9
// (K=4/BH=64, 561us) and grind per-iter next.
// Predicted: VGPR 80-128, FETCH ~96MB/launch, WRITE ~65.5MB, total
// ~470-530us, VALUBusy 45-55%.
// Per-iter engine unchanged: BH=64, single-buffered edges, 2 barriers/
// iter, unroll-4, interior-band mask elision, prefetch, 4 launches,
// partials in B region (last launch reads A).

#define IMG_H 1024
#define IMG_W 1024
#define IMG_N (IMG_H * IMG_W)
#define NIMG  16
#define NZ    32                    // 16 pred + 16 gt images
#define BH    64                    // output rows per band
#define NBANDS (IMG_H / BH)         // 16
#define K     5                     // fused skeleton iterations per launch
#define EW    258                   // 256 lanes + 2 guard slots
#define NBLK  (NZ * NBANDS)         // 512 blocks per launch
#define NITER (BH + 6 * K)          // 94 row-iterations

typedef _Float16 h2 __attribute__((ext_vector_type(2)));

__device__ __forceinline__ h2 hmin2(h2 a, h2 b) { return __builtin_elementwise_min(a, b); }
__device__ __forceinline__ h2 hmax2(h2 a, h2 b) { return __builtin_elementwise_max(a, b); }

union U32H { unsigned u; h2 h; };
__device__ __forceinline__ unsigned as_u(h2 h) { U32H t; t.h = h; return t.u; }
__device__ __forceinline__ h2 as_h2(unsigned u) { U32H t; t.u = u; return t.h; }

struct Hp { h2 lo, hi; };           // 4 image columns per lane
struct St { Hp hm1, hm2, m2, m3, q1, q2, x1, x2, x3, xc; };

// One pipeline stage. rmask: +inf pass / -inf force (maxpool row padding);
// only applied when MASKED (edge bands). Edge pair layout:
// e2[slot].x = {x_col0, m_col0} (read by LEFT-seeking neighbor at t+2);
// e2[slot].y = {x_col3, m_col3} (read at slot t). Single-buffered: caller
// guarantees barriers between prev writes / these reads / next writes.
template<int MASKED>
__device__ __forceinline__ Hp stage_step(
    St& s, h2 rmask, int t, const uint2 (&e2)[EW])
{
    h2 lp = as_h2(e2[t].y);        // left nbr's col3 {x, m}
    h2 rp = as_h2(e2[t + 2].x);    // right nbr's col0 {x, m}
    // h-min3 of x row
    h2 midx = (h2){s.xc.lo[1], s.xc.hi[0]};               // {x1, x2}
    h2 hlo = hmin2(hmin2((h2){lp[0], s.xc.lo[0]}, s.xc.lo), midx);
    h2 hhi = hmin2(hmin2(midx, s.xc.hi), (h2){s.xc.hi[1], rp[0]});
    // v-min3 (+ row-validity mask on edge bands only)
    h2 mlo, mhi;
    if constexpr (MASKED) {
        mlo = hmin2(hmin2(hmin2(s.hm1.lo, s.hm2.lo), hlo), rmask);
        mhi = hmin2(hmin2(hmin2(s.hm1.hi, s.hm2.hi), hhi), rmask);
    } else {
        mlo = hmin2(hmin2(s.hm1.lo, s.hm2.lo), hlo);
        mhi = hmin2(hmin2(s.hm1.hi, s.hm2.hi), hhi);
    }
    // h-max3 of m (previous iter's m, in m2; neighbor edges from LDS)
    h2 midm = (h2){s.m2.lo[1], s.m2.hi[0]};
    h2 qlo = hmax2(hmax2((h2){lp[1], s.m2.lo[0]}, s.m2.lo), midm);
    h2 qhi = hmax2(hmax2(midm, s.m2.hi), (h2){s.m2.hi[1], rp[1]});
    // v-max3
    h2 Mlo = hmax2(hmax2(s.q1.lo, s.q2.lo), qlo);
    h2 Mhi = hmax2(hmax2(s.q1.hi, s.q2.hi), qhi);
    // contour + relu update
    const h2 Z2 = (h2){(_Float16)0.f, (_Float16)0.f};
    h2 elo = hmax2(s.x3.lo - hmax2(Mlo - s.m3.lo, Z2), Z2);
    h2 ehi = hmax2(s.x3.hi - hmax2(Mhi - s.m3.hi, Z2), Z2);
    // ring shifts
    s.hm1 = s.hm2; s.hm2.lo = hlo; s.hm2.hi = hhi;
    s.m3  = s.m2;  s.m2.lo  = mlo; s.m2.hi  = mhi;
    s.q1  = s.q2;  s.q2.lo  = qlo; s.q2.hi  = qhi;
    s.x3  = s.x2;  s.x2 = s.x1;    s.x1 = s.xc;
    Hp e; e.lo = elo; e.hi = ehi;
    return e;
}

// Load one input row. MASKED: +inf outside the image. Unmasked (interior
// bands): every touched row is provably in-bounds -> unconditional load.
template<int FIRST, int MASKED>
__device__ __forceinline__ Hp load_row(
    int y, int c, const float* __restrict__ f32src,
    const unsigned short* __restrict__ bsrc)
{
    const _Float16 HINF = (_Float16)__builtin_huge_valf();
    Hp x; x.lo = (h2){HINF, HINF}; x.hi = (h2){HINF, HINF};
    if (!MASKED || (unsigned)y < (unsigned)IMG_H) {
        if constexpr (FIRST) {
            float4 f = *(const float4*)(f32src + (size_t)y * IMG_W + c);
            x.lo = (h2){(_Float16)f.x, (_Float16)f.y};
            x.hi = (h2){(_Float16)f.z, (_Float16)f.w};
        } else {
            uint2 u = *(const uint2*)(bsrc + (size_t)y * IMG_W + c);
            x.lo = as_h2(u.x);
            x.hi = as_h2(u.y);
        }
    }
    return x;
}

template<int FIRST, int LAST, int MASKED>
__device__ __forceinline__ void iter_step(
    int y, int t, int c, int r0, St (&st)[K], Hp& xn,
    const float* __restrict__ f32src, const unsigned short* __restrict__ bsrc,
    unsigned short* __restrict__ bdst, const float* __restrict__ oth,
    float& a1, float& a2, uint2 (&e2)[K][EW])
{
    const _Float16 HINF = (_Float16)__builtin_huge_valf();
    const h2 PINF2 = (h2){HINF, HINF};
    const h2 NINF2 = (h2){-HINF, -HINF};

    // issue the row-(y+2) load now; its value is consumed NEXT iteration,
    // so the global-load latency spans a full iteration body.
    Hp tnext = load_row<FIRST, MASKED>(y + 2, c, f32src, bsrc);

    __syncthreads();                         // prev-iter edge writes visible

    h2 rm = PINF2;
    if constexpr (MASKED)
        rm = ((unsigned)(y - (4 * (K - 1) + 1)) < (unsigned)IMG_H) ? PINF2 : NINF2;
    Hp eK = stage_step<MASKED>(st[K - 1], rm, t, e2[K - 1]);
    #pragma unroll
    for (int k = K - 2; k >= 0; --k) {
        if constexpr (MASKED)
            rm = ((unsigned)(y - 4 * k - 1) < (unsigned)IMG_H) ? PINF2 : NINF2;
        Hp e = stage_step<MASKED>(st[k], rm, t, e2[k]);
        if constexpr (MASKED) {
            h2 em = ((unsigned)(y - 4 * k - 3) < (unsigned)IMG_H) ? NINF2 : PINF2;
            st[k + 1].xc.lo = hmax2(e.lo, em);   // max(e,-inf)=e; max(e,+inf)=+inf
            st[k + 1].xc.hi = hmax2(e.hi, em);
        } else {
            st[k + 1].xc = e;
        }
    }
    st[0].xc = xn;                           // row y+1, loaded last iteration
    xn = tnext;

    __syncthreads();                         // all edge reads done

    // edge writes for next iteration (new xc + this iter's m, now in m2)
    #pragma unroll
    for (int k = 0; k < K; ++k) {
        e2[k][t + 1] = make_uint2(
            as_u((h2){st[k].xc.lo[0], st[k].m2.lo[0]}),
            as_u((h2){st[k].xc.hi[1], st[k].m2.hi[1]}));
    }

    int orow = y - (4 * (K - 1) + 3);        // y - 19
    if ((unsigned)(orow - r0) < (unsigned)BH) {
        if constexpr (!LAST) {
            *(uint2*)(bdst + (size_t)orow * IMG_W + c) =
                make_uint2(as_u(eK.lo), as_u(eK.hi));
        } else {
            float4 ov = *(const float4*)(oth + (size_t)orow * IMG_W + c);
            float e0 = (float)eK.lo[0], e1 = (float)eK.lo[1];
            float e2f = (float)eK.hi[0], e3 = (float)eK.hi[1];
            a1 += e0 * ov.x + e1 * ov.y + e2f * ov.z + e3 * ov.w;
            a2 += e0 + e1 + e2f + e3;
        }
    }
}

template<int FIRST, int LAST>
__global__ __launch_bounds__(256, 1) void skel(
    const unsigned short* __restrict__ src, unsigned short* __restrict__ dst,
    const float* __restrict__ pred32, const float* __restrict__ gt32,
    double* __restrict__ partials)
{
    __shared__ uint2 e2[K][EW];       // single-buffered edge exchange
    __shared__ double l1[4], l2[4];

    const int t = threadIdx.x, c = 4 * t;
    const int band = blockIdx.x, z = blockIdx.y;
    const int r0 = band * BH;
    const _Float16 HINF = (_Float16)__builtin_huge_valf();
    const h2 PINF2 = (h2){HINF, HINF};
    const h2 NINF2 = (h2){-HINF, -HINF};

    const float* f32src = (z < NIMG) ? pred32 + (size_t)z * IMG_N
                                     : gt32 + (size_t)(z - NIMG) * IMG_N;
    const unsigned short* bsrc = FIRST ? nullptr : src + (size_t)z * IMG_N;
    unsigned short* bdst = LAST ? nullptr : dst + (size_t)z * IMG_N;
    const float* oth = LAST ? ((z < NIMG) ? gt32 + (size_t)z * IMG_N
                                          : pred32 + (size_t)(z - NIMG) * IMG_N)
                            : nullptr;

    if (t < K) {
        // guard pairs: x=+inf (0x7C00 low), m=-inf (0xFC00 high)
        e2[t][0]      = make_uint2(0u, 0xFC007C00u);  // only .y read
        e2[t][EW - 1] = make_uint2(0xFC007C00u, 0u);  // only .x read
    }

    St st[K];
    #pragma unroll
    for (int k = 0; k < K; ++k) {
        st[k].hm1.lo = st[k].hm1.hi = PINF2;
        st[k].hm2.lo = st[k].hm2.hi = PINF2;
        st[k].m2.lo  = st[k].m2.hi  = NINF2;
        st[k].m3.lo  = st[k].m3.hi  = NINF2;
        st[k].q1.lo  = st[k].q1.hi  = NINF2;
        st[k].q2.lo  = st[k].q2.hi  = NINF2;
        st[k].x1.lo  = st[k].x1.hi  = PINF2;
        st[k].x2.lo  = st[k].x2.hi  = PINF2;
        st[k].x3.lo  = st[k].x3.hi  = PINF2;
        st[k].xc.lo  = st[k].xc.hi  = PINF2;
    }

    const int y0 = r0 - 2 * K;
    st[0].xc = load_row<FIRST, 1>(y0, c, f32src, bsrc);      // masked: cheap, once
    Hp xn    = load_row<FIRST, 1>(y0 + 1, c, f32src, bsrc);

    // prologue edge write (consumed by first iteration after its barrier)
    #pragma unroll
    for (int k = 0; k < K; ++k) {
        e2[k][t + 1] = make_uint2(
            as_u((h2){st[k].xc.lo[0], st[k].m2.lo[0]}),
            as_u((h2){st[k].xc.hi[1], st[k].m2.hi[1]}));
    }

    float a1 = 0.f, a2 = 0.f;
    // Interior bands (1..NBANDS-2): every rm/em mask and load bound is
    // provably constant across the whole y-range incl. warm-up
    // (y in [r0-27, r0+85] within [0,1024) for r0 in [64, 896]).
    // unroll 4 = x-ring period: ring-shift copies vanish at back-edge.
    if (band >= 1 && band <= NBANDS - 2) {
        #pragma unroll 4
        for (int i = 0; i < NITER; ++i)
            iter_step<FIRST, LAST, 0>(y0 + i, t, c, r0, st, xn, f32src, bsrc, bdst, oth, a1, a2, e2);
    } else {
        #pragma unroll 4
        for (int i = 0; i < NITER; ++i)
            iter_step<FIRST, LAST, 1>(y0 + i, t, c, r0, st, xn, f32src, bsrc, bdst, oth, a1, a2, e2);
    }

    if constexpr (LAST) {                    // per-block partials (no atomics)
        double d1 = a1, d2 = a2;
        for (int off = 32; off; off >>= 1) {
            d1 += __shfl_down(d1, off);
            d2 += __shfl_down(d2, off);
        }
        const int w = t >> 6;
        if ((t & 63) == 0) { l1[w] = d1; l2[w] = d2; }
        __syncthreads();
        if (t == 0) {
            int bid = z * NBANDS + band;
            partials[2 * bid]     = l1[0] + l1[1] + l1[2] + l1[3];
            partials[2 * bid + 1] = l2[0] + l2[1] + l2[2] + l2[3];
        }
    }
}

__global__ __launch_bounds__(256) void finalize(
    const double* __restrict__ pp, float* __restrict__ out)
{
    __shared__ double sh[4][4];
    double i1 = 0, i2 = 0, t1 = 0, t2 = 0;
    for (int i = threadIdx.x; i < NBLK; i += 256) {
        double a = pp[2 * i], b = pp[2 * i + 1];
        if (i < NIMG * NBANDS) { i1 += a; i2 += b; }   // z < 16: cl_pred side
        else                   { t1 += a; t2 += b; }   // z >= 16: skel_gt side
    }
    for (int off = 32; off; off >>= 1) {
        i1 += __shfl_down(i1, off); i2 += __shfl_down(i2, off);
        t1 += __shfl_down(t1, off); t2 += __shfl_down(t2, off);
    }
    const int w = threadIdx.x >> 6;
    if ((threadIdx.x & 63) == 0) { sh[0][w] = i1; sh[1][w] = i2; sh[2][w] = t1; sh[3][w] = t2; }
    __syncthreads();
    if (threadIdx.x == 0) {
        double s1 = 0, s2 = 0, s3 = 0, s4 = 0;
        for (int j = 0; j < 4; ++j) { s1 += sh[0][j]; s2 += sh[1][j]; s3 += sh[2][j]; s4 += sh[3][j]; }
        double iflat = (s1 + 1.0) / (s2 + 1.0);
        double tflat = (s3 + 1.0) / (s4 + 1.0);
        out[0] = (float)(1.0 - 2.0 * (iflat * tflat) / (iflat + tflat));
    }
}

extern "C" void kernel_launch(void* const* d_in, const int* in_sizes, int n_in,
                              void* d_out, int out_size, void* d_ws, size_t ws_size,
                              hipStream_t stream)
{
    const float* pred = (const float*)d_in[0];
    const float* gt   = (const float*)d_in[1];

    unsigned short* A = (unsigned short*)d_ws;            // 32 f16 images (64 MiB)
    unsigned short* B = A + (size_t)NZ * IMG_N;           // 32 f16 images
    // partials live in the B region: launch 4 reads A (A live!), B is dead.
    double* partials  = (double*)B;
    dim3 grid(NBANDS, NZ);                                // 16 bands x 32 images

    skel<1, 0><<<grid, 256, 0, stream>>>(nullptr, A, pred, gt, nullptr);  // iters 1-5
    skel<0, 0><<<grid, 256, 0, stream>>>(A, B, pred, gt, nullptr);        // 6-10
    skel<0, 0><<<grid, 256, 0, stream>>>(B, A, pred, gt, nullptr);        // 11-15
    skel<0, 1><<<grid, 256, 0, stream>>>(A, nullptr, pred, gt, partials); // 16-20 + sums

    finalize<<<1, 256, 0, stream>>>(partials, (float*)d_out);
}

// Round 14
// 559.583 us; speedup vs baseline: 1.5353x; 1.1169x over previous
//
#include <hip/hip_runtime.h>
#include <math.h>

// clDice loss on MI355X (gfx950).
// soft_skeletonize = 20 iterations of:
//   m = minpool3(x); contour = relu(maxpool3(m) - m); x = relu(x - contour)
// Round-24: r9 (K=4/BH=64, 561us best) + launch_bounds(256,1).
// r13 post-mortem: (256,1) IS the working register lever (VGPR 64->80,
// spills gone, FETCH==model). K=5 itself rejected per pre-committed rule:
// corrected accounting shows total stage-rows scale as (1+6K/BH) -- the
// warm-up halo grows ~K^2/BH, so K-fusion RAISES stage work (+7% at
// BH=64) while only amortizing barriers/loads; measured per-stage rate
// K=5@VGPR80 (0.673ns) ~= K=4@VGPR64 (0.70) -> wash on work, loss on
// total (625 vs 561). REVERT K=4. But that same comparison shows K=4's
// VGPR=64 allocation was clamped (allocator squeezing state into the
// 8-wave budget, paying in moves): relax it. BH=64 grid supplies only
// 2 blocks/CU = 8 waves/CU, and even VGPR 256 permits 8 waves/CU ->
// the (256,1) budget costs ZERO residency here.
// Single variable vs r9: attribute swap only.
// Predicted: VGPR 70-100 (gate >64), per-launch 126.8 -> ~113-120
// profiled, total ~520-540, FETCH ~90.6MB, VALUBusy ~50%.
// Failure: total >=560 with VGPR>64 -> register slack wasn't r9's
// inefficiency -> pivot to per-iter stall surgery / BH=32 variant.
// Engine: BH=64, K=4, single-buffered edges, 2 barriers/iter, unroll-4,
// interior-band mask elision, cross-iter prefetch, 5 launches + finalize,
// partials over A region (launch 5 reads B; A dead).

#define IMG_H 1024
#define IMG_W 1024
#define IMG_N (IMG_H * IMG_W)
#define NIMG  16
#define NZ    32                    // 16 pred + 16 gt images
#define BH    64                    // output rows per band
#define NBANDS (IMG_H / BH)         // 16
#define K     4                     // fused skeleton iterations per launch
#define EW    258                   // 256 lanes + 2 guard slots
#define NBLK  (NZ * NBANDS)         // 512 blocks per launch
#define NITER (BH + 6 * K)          // 88 row-iterations

typedef _Float16 h2 __attribute__((ext_vector_type(2)));

__device__ __forceinline__ h2 hmin2(h2 a, h2 b) { return __builtin_elementwise_min(a, b); }
__device__ __forceinline__ h2 hmax2(h2 a, h2 b) { return __builtin_elementwise_max(a, b); }

union U32H { unsigned u; h2 h; };
__device__ __forceinline__ unsigned as_u(h2 h) { U32H t; t.h = h; return t.u; }
__device__ __forceinline__ h2 as_h2(unsigned u) { U32H t; t.u = u; return t.h; }

struct Hp { h2 lo, hi; };           // 4 image columns per lane
struct St { Hp hm1, hm2, m2, m3, q1, q2, x1, x2, x3, xc; };

// One pipeline stage. rmask: +inf pass / -inf force (maxpool row padding);
// only applied when MASKED (edge bands). Edge pair layout:
// e2[slot].x = {x_col0, m_col0} (read by LEFT-seeking neighbor at t+2);
// e2[slot].y = {x_col3, m_col3} (read at slot t). Single-buffered: caller
// guarantees barriers between prev writes / these reads / next writes.
template<int MASKED>
__device__ __forceinline__ Hp stage_step(
    St& s, h2 rmask, int t, const uint2 (&e2)[EW])
{
    h2 lp = as_h2(e2[t].y);        // left nbr's col3 {x, m}
    h2 rp = as_h2(e2[t + 2].x);    // right nbr's col0 {x, m}
    // h-min3 of x row
    h2 midx = (h2){s.xc.lo[1], s.xc.hi[0]};               // {x1, x2}
    h2 hlo = hmin2(hmin2((h2){lp[0], s.xc.lo[0]}, s.xc.lo), midx);
    h2 hhi = hmin2(hmin2(midx, s.xc.hi), (h2){s.xc.hi[1], rp[0]});
    // v-min3 (+ row-validity mask on edge bands only)
    h2 mlo, mhi;
    if constexpr (MASKED) {
        mlo = hmin2(hmin2(hmin2(s.hm1.lo, s.hm2.lo), hlo), rmask);
        mhi = hmin2(hmin2(hmin2(s.hm1.hi, s.hm2.hi), hhi), rmask);
    } else {
        mlo = hmin2(hmin2(s.hm1.lo, s.hm2.lo), hlo);
        mhi = hmin2(hmin2(s.hm1.hi, s.hm2.hi), hhi);
    }
    // h-max3 of m (previous iter's m, in m2; neighbor edges from LDS)
    h2 midm = (h2){s.m2.lo[1], s.m2.hi[0]};
    h2 qlo = hmax2(hmax2((h2){lp[1], s.m2.lo[0]}, s.m2.lo), midm);
    h2 qhi = hmax2(hmax2(midm, s.m2.hi), (h2){s.m2.hi[1], rp[1]});
    // v-max3
    h2 Mlo = hmax2(hmax2(s.q1.lo, s.q2.lo), qlo);
    h2 Mhi = hmax2(hmax2(s.q1.hi, s.q2.hi), qhi);
    // contour + relu update
    const h2 Z2 = (h2){(_Float16)0.f, (_Float16)0.f};
    h2 elo = hmax2(s.x3.lo - hmax2(Mlo - s.m3.lo, Z2), Z2);
    h2 ehi = hmax2(s.x3.hi - hmax2(Mhi - s.m3.hi, Z2), Z2);
    // ring shifts
    s.hm1 = s.hm2; s.hm2.lo = hlo; s.hm2.hi = hhi;
    s.m3  = s.m2;  s.m2.lo  = mlo; s.m2.hi  = mhi;
    s.q1  = s.q2;  s.q2.lo  = qlo; s.q2.hi  = qhi;
    s.x3  = s.x2;  s.x2 = s.x1;    s.x1 = s.xc;
    Hp e; e.lo = elo; e.hi = ehi;
    return e;
}

// Load one input row. MASKED: +inf outside the image. Unmasked (interior
// bands): every touched row is provably in-bounds -> unconditional load.
template<int FIRST, int MASKED>
__device__ __forceinline__ Hp load_row(
    int y, int c, const float* __restrict__ f32src,
    const unsigned short* __restrict__ bsrc)
{
    const _Float16 HINF = (_Float16)__builtin_huge_valf();
    Hp x; x.lo = (h2){HINF, HINF}; x.hi = (h2){HINF, HINF};
    if (!MASKED || (unsigned)y < (unsigned)IMG_H) {
        if constexpr (FIRST) {
            float4 f = *(const float4*)(f32src + (size_t)y * IMG_W + c);
            x.lo = (h2){(_Float16)f.x, (_Float16)f.y};
            x.hi = (h2){(_Float16)f.z, (_Float16)f.w};
        } else {
            uint2 u = *(const uint2*)(bsrc + (size_t)y * IMG_W + c);
            x.lo = as_h2(u.x);
            x.hi = as_h2(u.y);
        }
    }
    return x;
}

template<int FIRST, int LAST, int MASKED>
__device__ __forceinline__ void iter_step(
    int y, int t, int c, int r0, St (&st)[K], Hp& xn,
    const float* __restrict__ f32src, const unsigned short* __restrict__ bsrc,
    unsigned short* __restrict__ bdst, const float* __restrict__ oth,
    float& a1, float& a2, uint2 (&e2)[K][EW])
{
    const _Float16 HINF = (_Float16)__builtin_huge_valf();
    const h2 PINF2 = (h2){HINF, HINF};
    const h2 NINF2 = (h2){-HINF, -HINF};

    // issue the row-(y+2) load now; its value is consumed NEXT iteration,
    // so the global-load latency spans a full iteration body.
    Hp tnext = load_row<FIRST, MASKED>(y + 2, c, f32src, bsrc);

    __syncthreads();                         // prev-iter edge writes visible

    h2 rm = PINF2;
    if constexpr (MASKED)
        rm = ((unsigned)(y - (4 * (K - 1) + 1)) < (unsigned)IMG_H) ? PINF2 : NINF2;
    Hp eK = stage_step<MASKED>(st[K - 1], rm, t, e2[K - 1]);
    #pragma unroll
    for (int k = K - 2; k >= 0; --k) {
        if constexpr (MASKED)
            rm = ((unsigned)(y - 4 * k - 1) < (unsigned)IMG_H) ? PINF2 : NINF2;
        Hp e = stage_step<MASKED>(st[k], rm, t, e2[k]);
        if constexpr (MASKED) {
            h2 em = ((unsigned)(y - 4 * k - 3) < (unsigned)IMG_H) ? NINF2 : PINF2;
            st[k + 1].xc.lo = hmax2(e.lo, em);   // max(e,-inf)=e; max(e,+inf)=+inf
            st[k + 1].xc.hi = hmax2(e.hi, em);
        } else {
            st[k + 1].xc = e;
        }
    }
    st[0].xc = xn;                           // row y+1, loaded last iteration
    xn = tnext;

    __syncthreads();                         // all edge reads done

    // edge writes for next iteration (new xc + this iter's m, now in m2)
    #pragma unroll
    for (int k = 0; k < K; ++k) {
        e2[k][t + 1] = make_uint2(
            as_u((h2){st[k].xc.lo[0], st[k].m2.lo[0]}),
            as_u((h2){st[k].xc.hi[1], st[k].m2.hi[1]}));
    }

    int orow = y - (4 * (K - 1) + 3);        // y - 15
    if ((unsigned)(orow - r0) < (unsigned)BH) {
        if constexpr (!LAST) {
            *(uint2*)(bdst + (size_t)orow * IMG_W + c) =
                make_uint2(as_u(eK.lo), as_u(eK.hi));
        } else {
            float4 ov = *(const float4*)(oth + (size_t)orow * IMG_W + c);
            float e0 = (float)eK.lo[0], e1 = (float)eK.lo[1];
            float e2f = (float)eK.hi[0], e3 = (float)eK.hi[1];
            a1 += e0 * ov.x + e1 * ov.y + e2f * ov.z + e3 * ov.w;
            a2 += e0 + e1 + e2f + e3;
        }
    }
}

template<int FIRST, int LAST>
__global__ __launch_bounds__(256, 1) void skel(
    const unsigned short* __restrict__ src, unsigned short* __restrict__ dst,
    const float* __restrict__ pred32, const float* __restrict__ gt32,
    double* __restrict__ partials)
{
    __shared__ uint2 e2[K][EW];       // single-buffered edge exchange
    __shared__ double l1[4], l2[4];

    const int t = threadIdx.x, c = 4 * t;
    const int band = blockIdx.x, z = blockIdx.y;
    const int r0 = band * BH;
    const _Float16 HINF = (_Float16)__builtin_huge_valf();
    const h2 PINF2 = (h2){HINF, HINF};
    const h2 NINF2 = (h2){-HINF, -HINF};

    const float* f32src = (z < NIMG) ? pred32 + (size_t)z * IMG_N
                                     : gt32 + (size_t)(z - NIMG) * IMG_N;
    const unsigned short* bsrc = FIRST ? nullptr : src + (size_t)z * IMG_N;
    unsigned short* bdst = LAST ? nullptr : dst + (size_t)z * IMG_N;
    const float* oth = LAST ? ((z < NIMG) ? gt32 + (size_t)z * IMG_N
                                          : pred32 + (size_t)(z - NIMG) * IMG_N)
                            : nullptr;

    if (t < K) {
        // guard pairs: x=+inf (0x7C00 low), m=-inf (0xFC00 high)
        e2[t][0]      = make_uint2(0u, 0xFC007C00u);  // only .y read
        e2[t][EW - 1] = make_uint2(0xFC007C00u, 0u);  // only .x read
    }

    St st[K];
    #pragma unroll
    for (int k = 0; k < K; ++k) {
        st[k].hm1.lo = st[k].hm1.hi = PINF2;
        st[k].hm2.lo = st[k].hm2.hi = PINF2;
        st[k].m2.lo  = st[k].m2.hi  = NINF2;
        st[k].m3.lo  = st[k].m3.hi  = NINF2;
        st[k].q1.lo  = st[k].q1.hi  = NINF2;
        st[k].q2.lo  = st[k].q2.hi  = NINF2;
        st[k].x1.lo  = st[k].x1.hi  = PINF2;
        st[k].x2.lo  = st[k].x2.hi  = PINF2;
        st[k].x3.lo  = st[k].x3.hi  = PINF2;
        st[k].xc.lo  = st[k].xc.hi  = PINF2;
    }

    const int y0 = r0 - 2 * K;
    st[0].xc = load_row<FIRST, 1>(y0, c, f32src, bsrc);      // masked: cheap, once
    Hp xn    = load_row<FIRST, 1>(y0 + 1, c, f32src, bsrc);

    // prologue edge write (consumed by first iteration after its barrier)
    #pragma unroll
    for (int k = 0; k < K; ++k) {
        e2[k][t + 1] = make_uint2(
            as_u((h2){st[k].xc.lo[0], st[k].m2.lo[0]}),
            as_u((h2){st[k].xc.hi[1], st[k].m2.hi[1]}));
    }

    float a1 = 0.f, a2 = 0.f;
    // Interior bands (1..NBANDS-2): every rm/em mask and load bound is
    // provably constant across the whole y-range incl. warm-up
    // (y in [r0-21, r0+81] within [0,1024) for r0 in [64, 896]).
    // unroll 4 = x-ring period: ring-shift copies vanish at back-edge.
    if (band >= 1 && band <= NBANDS - 2) {
        #pragma unroll 4
        for (int i = 0; i < NITER; ++i)
            iter_step<FIRST, LAST, 0>(y0 + i, t, c, r0, st, xn, f32src, bsrc, bdst, oth, a1, a2, e2);
    } else {
        #pragma unroll 4
        for (int i = 0; i < NITER; ++i)
            iter_step<FIRST, LAST, 1>(y0 + i, t, c, r0, st, xn, f32src, bsrc, bdst, oth, a1, a2, e2);
    }

    if constexpr (LAST) {                    // per-block partials (no atomics)
        double d1 = a1, d2 = a2;
        for (int off = 32; off; off >>= 1) {
            d1 += __shfl_down(d1, off);
            d2 += __shfl_down(d2, off);
        }
        const int w = t >> 6;
        if ((t & 63) == 0) { l1[w] = d1; l2[w] = d2; }
        __syncthreads();
        if (t == 0) {
            int bid = z * NBANDS + band;
            partials[2 * bid]     = l1[0] + l1[1] + l1[2] + l1[3];
            partials[2 * bid + 1] = l2[0] + l2[1] + l2[2] + l2[3];
        }
    }
}

__global__ __launch_bounds__(256) void finalize(
    const double* __restrict__ pp, float* __restrict__ out)
{
    __shared__ double sh[4][4];
    double i1 = 0, i2 = 0, t1 = 0, t2 = 0;
    for (int i = threadIdx.x; i < NBLK; i += 256) {
        double a = pp[2 * i], b = pp[2 * i + 1];
        if (i < NIMG * NBANDS) { i1 += a; i2 += b; }   // z < 16: cl_pred side
        else                   { t1 += a; t2 += b; }   // z >= 16: skel_gt side
    }
    for (int off = 32; off; off >>= 1) {
        i1 += __shfl_down(i1, off); i2 += __shfl_down(i2, off);
        t1 += __shfl_down(t1, off); t2 += __shfl_down(t2, off);
    }
    const int w = threadIdx.x >> 6;
    if ((threadIdx.x & 63) == 0) { sh[0][w] = i1; sh[1][w] = i2; sh[2][w] = t1; sh[3][w] = t2; }
    __syncthreads();
    if (threadIdx.x == 0) {
        double s1 = 0, s2 = 0, s3 = 0, s4 = 0;
        for (int j = 0; j < 4; ++j) { s1 += sh[0][j]; s2 += sh[1][j]; s3 += sh[2][j]; s4 += sh[3][j]; }
        double iflat = (s1 + 1.0) / (s2 + 1.0);
        double tflat = (s3 + 1.0) / (s4 + 1.0);
        out[0] = (float)(1.0 - 2.0 * (iflat * tflat) / (iflat + tflat));
    }
}

extern "C" void kernel_launch(void* const* d_in, const int* in_sizes, int n_in,
                              void* d_out, int out_size, void* d_ws, size_t ws_size,
                              hipStream_t stream)
{
    const float* pred = (const float*)d_in[0];
    const float* gt   = (const float*)d_in[1];

    unsigned short* A = (unsigned short*)d_ws;            // 32 f16 images (64 MiB)
    unsigned short* B = A + (size_t)NZ * IMG_N;           // 32 f16 images
    double* partials  = (double*)d_ws;                    // overlaps A; A is dead
                                                          // when launch 5 (reads B) runs
    dim3 grid(NBANDS, NZ);                                // 16 bands x 32 images

    skel<1, 0><<<grid, 256, 0, stream>>>(nullptr, A, pred, gt, nullptr);  // iters 1-4
    skel<0, 0><<<grid, 256, 0, stream>>>(A, B, pred, gt, nullptr);        // 5-8
    skel<0, 0><<<grid, 256, 0, stream>>>(B, A, pred, gt, nullptr);        // 9-12
    skel<0, 0><<<grid, 256, 0, stream>>>(A, B, pred, gt, nullptr);        // 13-16
    skel<0, 1><<<grid, 256, 0, stream>>>(B, nullptr, pred, gt, partials); // 17-20 + sums

    finalize<<<1, 256, 0, stream>>>(partials, (float*)d_out);
}